// Round 1
// baseline (55.158 us; speedup 1.0000x reference)
//
#include <hip/hip_runtime.h>
#include <hip/hip_bf16.h>
#include <math.h>

// Scalar damped-Newton minimization of a degree-6 polynomial.
// Mirrors the JAX reference exactly:
//   d1 = deriv(poly), d2 = deriv(d1)
//   while (g2 > 1e-12 && it < 100):
//     g = d1(x); h = d2(x)
//     step = h > 0 ? g/h : 0.1*g
//     x -= step; g2 = d1(x)^2; it++
// Single wave, single active lane — latency-bound, nothing to parallelize.

#define MAX_ITER 100
#define GRAD_SQ_TOL 1e-12f

// polyval matching jnp.sum(poly * x**arange): power-series accumulation,
// lowest degree first (not Horner), to track the reference trajectory.
template <int N>
__device__ __forceinline__ float polyval_ps(const float* p, float x) {
    float acc = 0.0f;
    float xp = 1.0f;
#pragma unroll
    for (int i = 0; i < N; ++i) {
        acc += p[i] * xp;
        xp *= x;
    }
    return acc;
}

__global__ void __launch_bounds__(64)
polymin_kernel(const float* __restrict__ poly,
               const float* __restrict__ x_init,
               float* __restrict__ out) {
    if (threadIdx.x != 0) return;

    // Load 7 coefficients (lowest-degree-first).
    float c[7];
#pragma unroll
    for (int i = 0; i < 7; ++i) c[i] = poly[i];

    // First and second derivative coefficients.
    float d1[6];
#pragma unroll
    for (int i = 0; i < 6; ++i) d1[i] = c[i + 1] * (float)(i + 1);
    float d2[5];
#pragma unroll
    for (int i = 0; i < 5; ++i) d2[i] = d1[i + 1] * (float)(i + 1);

    float x = x_init[0];
    float g2 = INFINITY;
    int it = 0;

    while (g2 > GRAD_SQ_TOL && it < MAX_ITER) {
        float g = polyval_ps<6>(d1, x);
        float h = polyval_ps<5>(d2, x);
        float step = (h > 0.0f) ? (g / h) : (0.1f * g);
        float x_new = x - step;
        float g_new = polyval_ps<6>(d1, x_new);
        x = x_new;
        g2 = g_new * g_new;
        ++it;
    }

    out[0] = x;
}

extern "C" void kernel_launch(void* const* d_in, const int* in_sizes, int n_in,
                              void* d_out, int out_size, void* d_ws, size_t ws_size,
                              hipStream_t stream) {
    const float* poly   = (const float*)d_in[0];  // 7 coeffs, lowest-degree-first
    const float* x_init = (const float*)d_in[1];  // scalar
    float* out = (float*)d_out;                   // scalar x_min

    polymin_kernel<<<1, 64, 0, stream>>>(poly, x_init, out);
}